// Round 4
// baseline (477.565 us; speedup 1.0000x reference)
//
#include <hip/hip_runtime.h>
#include <math.h>

// ---------------------------------------------------------------------------
// TransformerBlock: B=2 S=2048 DIM=1024 H=16 hd=64 FFN=4096, fp32 in/out.
// bf16 MFMA everywhere. R3: attention K/V staging double-buffered — stage of
// chunk c+1 issued right after the barrier, in flight across compute of
// chunk c, drained by the NEXT barrier (true prefetch; the m97 2-barrier
// stall doesn't apply because the issue point exists here). 1 barrier/chunk.
// ---------------------------------------------------------------------------

#define DIMSZ 1024
#define SEQ   2048
#define BATCH 2
#define NHEAD 16
#define HD    64
#define FFNSZ 4096
#define ROWS  (BATCH*SEQ)   // 4096

typedef __attribute__((ext_vector_type(8))) short bf8_t;   // 8 x bf16 (4 VGPR)
typedef __attribute__((ext_vector_type(4))) float f4_t;    // 4 x f32

// round-to-nearest-even float -> bf16 (bit pattern)
__device__ __forceinline__ unsigned short f2bf(float f) {
  union { float f; unsigned u; } c; c.f = f;
  unsigned u = c.u;
  return (unsigned short)((u + 0x7fffu + ((u >> 16) & 1u)) >> 16);
}

__device__ __forceinline__ float fast_exp2(float x) {
#if __has_builtin(__builtin_amdgcn_exp2f)
  return __builtin_amdgcn_exp2f(x);   // v_exp_f32 is natively 2^x
#else
  return exp2f(x);
#endif
}

// pack hi16(a),hi16(b) -> (bf16(b)<<16)|bf16(a)  [truncating cvt, 1 instr]
__device__ __forceinline__ unsigned int pk_trunc_bf16(float a, float b) {
#if __has_builtin(__builtin_amdgcn_perm)
  return __builtin_amdgcn_perm(__float_as_uint(b), __float_as_uint(a), 0x07060302u);
#else
  return (__float_as_uint(b) & 0xffff0000u) | (__float_as_uint(a) >> 16);
#endif
}

__device__ __forceinline__ void async16(const void* g, void* l) {
  __builtin_amdgcn_global_load_lds((const __attribute__((address_space(1))) void*)g,
                                   (__attribute__((address_space(3))) void*)l,
                                   16, 0, 0);
}

__device__ __forceinline__ f4_t mfma_bf16(bf8_t a, bf8_t b, f4_t c) {
  return __builtin_amdgcn_mfma_f32_16x16x32_bf16(a, b, c, 0, 0, 0);
}

// ---------------------------------------------------------------------------
// LayerNorm: one wave per row of 1024 fp32 -> bf16 out.
// ---------------------------------------------------------------------------
__global__ __launch_bounds__(256) void ln_kernel(const float* __restrict__ x,
                                                 const float* __restrict__ w,
                                                 const float* __restrict__ b,
                                                 unsigned short* __restrict__ out) {
  int row  = blockIdx.x * 4 + (threadIdx.x >> 6);
  int lane = threadIdx.x & 63;
  const float4* xr = (const float4*)(x + (size_t)row * DIMSZ);
  float4 v[4];
  float s = 0.f, s2 = 0.f;
#pragma unroll
  for (int i = 0; i < 4; ++i) {
    v[i] = xr[lane + 64*i];
    s  += (v[i].x + v[i].y) + (v[i].z + v[i].w);
    s2 += (v[i].x*v[i].x + v[i].y*v[i].y) + (v[i].z*v[i].z + v[i].w*v[i].w);
  }
#pragma unroll
  for (int off = 32; off; off >>= 1) {
    s  += __shfl_xor(s,  off);
    s2 += __shfl_xor(s2, off);
  }
  float mean = s * (1.f/DIMSZ);
  float var  = s2 * (1.f/DIMSZ) - mean*mean;
  float rstd = rsqrtf(var + 1e-12f);
  const float4* wr = (const float4*)w;
  const float4* br = (const float4*)b;
#pragma unroll
  for (int i = 0; i < 4; ++i) {
    float4 wv = wr[lane + 64*i];
    float4 bv = br[lane + 64*i];
    ushort4 o;
    o.x = f2bf((v[i].x - mean) * rstd * wv.x + bv.x);
    o.y = f2bf((v[i].y - mean) * rstd * wv.y + bv.y);
    o.z = f2bf((v[i].z - mean) * rstd * wv.z + bv.z);
    o.w = f2bf((v[i].w - mean) * rstd * wv.w + bv.w);
    *(ushort4*)(out + (size_t)row * DIMSZ + (size_t)(lane + 64*i) * 4) = o;
  }
}

// ---------------------------------------------------------------------------
// Weight cast+transpose, 4 square 1024x1024 weights in one launch (grid.z).
// ---------------------------------------------------------------------------
__global__ __launch_bounds__(256) void wtrans4_kernel(const float* __restrict__ w0,
                                                      const float* __restrict__ w1,
                                                      const float* __restrict__ w2,
                                                      const float* __restrict__ w3,
                                                      unsigned short* __restrict__ o0,
                                                      unsigned short* __restrict__ o1,
                                                      unsigned short* __restrict__ o2,
                                                      unsigned short* __restrict__ o3) {
  const int K = 1024, N = 1024;
  const float* w = (blockIdx.z == 0) ? w0 : (blockIdx.z == 1) ? w1 : (blockIdx.z == 2) ? w2 : w3;
  unsigned short* wT = (blockIdx.z == 0) ? o0 : (blockIdx.z == 1) ? o1 : (blockIdx.z == 2) ? o2 : o3;
  __shared__ float t[32][33];
  int tx = threadIdx.x & 31, ty = threadIdx.x >> 5;
  int n0 = blockIdx.x * 32, k0 = blockIdx.y * 32;
#pragma unroll
  for (int i = 0; i < 4; ++i)
    t[ty + 8*i][tx] = w[(size_t)(k0 + ty + 8*i) * N + n0 + tx];
  __syncthreads();
#pragma unroll
  for (int i = 0; i < 4; ++i)
    wT[(size_t)(n0 + ty + 8*i) * K + k0 + tx] = f2bf(t[tx][ty + 8*i]);
}

// generic single-weight version (w1, w2)
__global__ __launch_bounds__(256) void wtrans_kernel(const float* __restrict__ w,
                                                     unsigned short* __restrict__ wT,
                                                     int K, int N) {
  __shared__ float t[32][33];
  int tx = threadIdx.x & 31, ty = threadIdx.x >> 5;
  int n0 = blockIdx.x * 32, k0 = blockIdx.y * 32;
#pragma unroll
  for (int i = 0; i < 4; ++i)
    t[ty + 8*i][tx] = w[(size_t)(k0 + ty + 8*i) * N + n0 + tx];
  __syncthreads();
#pragma unroll
  for (int i = 0; i < 4; ++i)
    wT[(size_t)(n0 + ty + 8*i) * K + k0 + tx] = f2bf(t[tx][ty + 8*i]);
}

// ---------------------------------------------------------------------------
// V transpose: qkv[(b*S+s)*3072 + 2048 + h*64 + d] -> vt[(bh*64+d)*S + s]
// ---------------------------------------------------------------------------
__global__ __launch_bounds__(256) void vt_kernel(const unsigned short* __restrict__ qkv,
                                                 unsigned short* __restrict__ vt) {
  __shared__ unsigned short tile[64][65];
  int bh = blockIdx.y, b = bh >> 4, h = bh & 15;
  int s0 = blockIdx.x * 64;
  int tx = threadIdx.x & 63, ty = threadIdx.x >> 6;
#pragma unroll
  for (int i = 0; i < 16; ++i) {
    int s = ty + i*4;
    tile[s][tx] = qkv[((size_t)(b*SEQ) + s0 + s) * 3072 + 2048 + h*HD + tx];
  }
  __syncthreads();
#pragma unroll
  for (int i = 0; i < 16; ++i) {
    int d = ty + i*4;
    vt[((size_t)bh * HD + d) * SEQ + s0 + tx] = tile[tx][d];
  }
}

// ---------------------------------------------------------------------------
// GEMM: C[M,N] = epi( A[M,K] @ Bt[N,K]^T )   (m97 structure, unchanged)
// ---------------------------------------------------------------------------
template<int EPI>
__global__ __launch_bounds__(256) void gemm_bt(const unsigned short* __restrict__ A,
                                               const unsigned short* __restrict__ Bt,
                                               void* __restrict__ Cv,
                                               const float* __restrict__ res,
                                               int M, int N, int K) {
  __shared__ unsigned short As[128*32];
  __shared__ unsigned short Bs[128*32];
  int tid  = threadIdx.x;
  int wv   = tid >> 6, lane = tid & 63, quad = lane >> 4, ml = lane & 15;
  int wrow = (wv >> 1) * 64, wcol = (wv & 1) * 64;
  const unsigned short* Ab = A  + (size_t)blockIdx.y * 128 * K;
  const unsigned short* Bb = Bt + (size_t)blockIdx.x * 128 * K;

  f4_t acc[4][4];
#pragma unroll
  for (int i = 0; i < 4; ++i)
#pragma unroll
    for (int j = 0; j < 4; ++j) acc[i][j] = (f4_t){0.f, 0.f, 0.f, 0.f};

  int r0 = tid >> 2, c0 = (tid & 3) * 8;

  for (int k0 = 0; k0 < K; k0 += 32) {
    async16(Ab + (size_t)r0 * K + k0 + c0,        &As[(size_t)tid * 8]);
    async16(Ab + (size_t)(r0+64) * K + k0 + c0,   &As[((size_t)tid + 256) * 8]);
    async16(Bb + (size_t)r0 * K + k0 + c0,        &Bs[(size_t)tid * 8]);
    async16(Bb + (size_t)(r0+64) * K + k0 + c0,   &Bs[((size_t)tid + 256) * 8]);
    __syncthreads();

    bf8_t af[4], bfr[4];
#pragma unroll
    for (int i = 0; i < 4; ++i)
      af[i] = *(const bf8_t*)(&As[(wrow + i*16 + ml) * 32 + quad * 8]);
#pragma unroll
    for (int j = 0; j < 4; ++j)
      bfr[j] = *(const bf8_t*)(&Bs[(wcol + j*16 + ml) * 32 + quad * 8]);
#pragma unroll
    for (int i = 0; i < 4; ++i)
#pragma unroll
      for (int j = 0; j < 4; ++j)
        acc[i][j] = mfma_bf16(af[i], bfr[j], acc[i][j]);
    __syncthreads();
  }

#pragma unroll
  for (int i = 0; i < 4; ++i) {
    int grow = blockIdx.y * 128 + wrow + i*16 + quad*4;
#pragma unroll
    for (int j = 0; j < 4; ++j) {
      int gcol = blockIdx.x * 128 + wcol + j*16 + ml;
#pragma unroll
      for (int r = 0; r < 4; ++r) {
        size_t off = (size_t)(grow + r) * N + gcol;
        float v = acc[i][j][r];
        if constexpr (EPI == 2) {
          ((float*)Cv)[off] = res[off] + v;
        } else {
          if constexpr (EPI == 1)
            v = 0.5f * v * (1.f + erff(v * 0.70710678118654752f));
          ((unsigned short*)Cv)[off] = f2bf(v);
        }
      }
    }
  }
}

// ---------------------------------------------------------------------------
// Flash attention, R3: double-buffered K/V staging.
// grid = (S/64, B*H), block 256 (4 waves x 16 q-rows). 64-key chunks.
// Pipeline per 2 chunks:  sync | stage(c+1->buf1), mask(c+1) | compute(buf0)
//                       | sync | stage(c+2->buf0), mask(c+2) | compute(buf1)
// Every stage has a full compute phase in flight before its consuming
// barrier. Fixed-base exp2 softmax (shift-invariance; |s|~O(3)).
// S^T = K·Q^T; O^T = V^T·P^T; P wave-private LDS (lgkmcnt-ordered).
// ---------------------------------------------------------------------------
__global__ __launch_bounds__(256) void attn_kernel(const unsigned short* __restrict__ qkv,
                                                   const unsigned short* __restrict__ vt,
                                                   const float* __restrict__ mask,
                                                   unsigned short* __restrict__ attnout) {
  __shared__ unsigned short Ks[2][2][64][32];   // [buf][d-half][key][d32] 16 KB
  __shared__ unsigned short Vs[2][2][64][32];   // [buf][key-half][d][k32] 16 KB
  __shared__ unsigned short Ps[4][16][72];      // per-wave P^T, padded     9 KB

  int bh = blockIdx.y, b = bh >> 4, h = bh & 15;
  int tid = threadIdx.x;
  int wv = tid >> 6, lane = tid & 63;
  int quad = lane >> 4, ml = lane & 15;
  int q0 = blockIdx.x * 64;
  int q  = q0 + wv * 16 + ml;               // this lane's q row (seq pos)

  const unsigned short* qrow = qkv + ((size_t)(b*SEQ) + q) * 3072 + h*HD;
  bf8_t qf0 = *(const bf8_t*)(qrow + quad*8);
  bf8_t qf1 = *(const bf8_t*)(qrow + 32 + quad*8);

  const unsigned short* kbase = qkv + (size_t)(b*SEQ) * 3072 + DIMSZ + h*HD;
  const unsigned short* vbase = vt + (size_t)bh * HD * SEQ;
  const float* mrow = mask + (size_t)q * SEQ;

  int srow = tid >> 2;            // 0..63
  int scol = (tid & 3) * 8;       // 0,8,16,24 (ushorts)

  f4_t O[4];
#pragma unroll
  for (int dt = 0; dt < 4; ++dt) O[dt] = (f4_t){0.f, 0.f, 0.f, 0.f};
  float lR = 0.f;

  const float C1 = 0.18033688011112042f;   // 0.125 * log2(e)
  const float C2 = 1.4426950408889634f;    // log2(e)

  // --- helpers -------------------------------------------------------------
  auto stage = [&](int t0, int buf) {
#pragma unroll
    for (int dh = 0; dh < 2; ++dh)
      async16(kbase + (size_t)(t0 + srow) * 3072 + dh*32 + scol,
              &Ks[buf][dh][0][0] + (size_t)tid * 8);
#pragma unroll
    for (int kc = 0; kc < 2; ++kc)
      async16(vbase + (size_t)srow * SEQ + t0 + kc*32 + scol,
              &Vs[buf][kc][0][0] + (size_t)tid * 8);
  };
  auto loadmask = [&](int t0, float4* mv) {
#pragma unroll
    for (int mt = 0; mt < 4; ++mt)
      mv[mt] = *(const float4*)(mrow + t0 + mt*16 + quad*4);
  };
  auto compute = [&](int buf, const float4* mv) {
#pragma unroll
    for (int mt = 0; mt < 4; ++mt) {
      bf8_t kf0 = *(const bf8_t*)(&Ks[buf][0][mt*16 + ml][quad*8]);
      bf8_t kf1 = *(const bf8_t*)(&Ks[buf][1][mt*16 + ml][quad*8]);
      f4_t s = (f4_t){0.f, 0.f, 0.f, 0.f};
      s = mfma_bf16(kf0, qf0, s);
      s = mfma_bf16(kf1, qf1, s);
      float p0 = fast_exp2(fmaf(s[0], C1, mv[mt].x * C2));
      float p1 = fast_exp2(fmaf(s[1], C1, mv[mt].y * C2));
      float p2 = fast_exp2(fmaf(s[2], C1, mv[mt].z * C2));
      float p3 = fast_exp2(fmaf(s[3], C1, mv[mt].w * C2));
      lR += (p0 + p1) + (p2 + p3);
      uint2 pk;
      pk.x = pk_trunc_bf16(p0, p1);
      pk.y = pk_trunc_bf16(p2, p3);
      *(uint2*)(&Ps[wv][ml][mt*16 + quad*4]) = pk;
    }
#pragma unroll
    for (int kc = 0; kc < 2; ++kc) {
      bf8_t pf = *(const bf8_t*)(&Ps[wv][ml][kc*32 + quad*8]);
#pragma unroll
      for (int dt = 0; dt < 4; ++dt) {
        bf8_t vf = *(const bf8_t*)(&Vs[buf][kc][dt*16 + ml][quad*8]);
        O[dt] = mfma_bf16(vf, pf, O[dt]);
      }
    }
  };
  // -------------------------------------------------------------------------

  float4 mcur[4], mnxt[4];
  stage(0, 0);
  loadmask(0, mcur);

#pragma unroll 1
  for (int c = 0; c < SEQ/64; c += 2) {
    __syncthreads();                       // buf0(chunk c) ready; buf1 reads of c-1 done
    loadmask((c+1)*64, mnxt);
    stage((c+1)*64, 1);                    // in flight across compute(buf0)
    compute(0, mcur);
    __syncthreads();                       // buf1(chunk c+1) ready; buf0 reads done
    if (c + 2 < SEQ/64) {
      loadmask((c+2)*64, mcur);
      stage((c+2)*64, 0);                  // in flight across compute(buf1)
    }
    compute(1, mnxt);
  }

  lR += __shfl_xor(lR, 16);
  lR += __shfl_xor(lR, 32);
  float linv = 1.f / lR;
#pragma unroll
  for (int dt = 0; dt < 4; ++dt) {
    ushort4 o;
    o.x = f2bf(O[dt][0] * linv);
    o.y = f2bf(O[dt][1] * linv);
    o.z = f2bf(O[dt][2] * linv);
    o.w = f2bf(O[dt][3] * linv);
    *(ushort4*)(attnout + ((size_t)(b*SEQ) + q) * DIMSZ + h*HD + dt*16 + quad*4) = o;
  }
}

// ---------------------------------------------------------------------------
extern "C" void kernel_launch(void* const* d_in, const int* in_sizes, int n_in,
                              void* d_out, int out_size, void* d_ws, size_t ws_size,
                              hipStream_t stream) {
  const float* x    = (const float*)d_in[0];
  const float* mask = (const float*)d_in[1];
  const float* wq   = (const float*)d_in[2];
  const float* wk   = (const float*)d_in[3];
  const float* wvp  = (const float*)d_in[4];
  const float* wo   = (const float*)d_in[5];
  const float* w1   = (const float*)d_in[6];
  const float* w2   = (const float*)d_in[7];
  const float* ln1w = (const float*)d_in[8];
  const float* ln1b = (const float*)d_in[9];
  const float* ln2w = (const float*)d_in[10];
  const float* ln2b = (const float*)d_in[11];
  float* out = (float*)d_out;

  char* ws = (char*)d_ws;
  unsigned short* wqkvT  = (unsigned short*)(ws + 0);           //  6 MiB [3072][1024]
  unsigned short* woT    = (unsigned short*)(ws + 6291456);     //  2 MiB [1024][1024]
  unsigned short* w1T    = (unsigned short*)(ws + 8388608);     //  8 MiB [4096][1024]
  unsigned short* w2T    = (unsigned short*)(ws + 16777216);    //  8 MiB [1024][4096]
  unsigned short* attno  = (unsigned short*)(ws + 25165824);    //  8 MiB [4096][1024]
  float*          x2     = (float*)         (ws + 33554432);    // 16 MiB [4096][1024]
  unsigned short* hbuf   = (unsigned short*)(ws + 50331648);    //  8 MiB h1 then h2
  unsigned short* qkvb   = (unsigned short*)(ws + 58720256);    // 24 MiB [4096][3072]
  unsigned short* vtb    = (unsigned short*)(ws + 83886080);    //  8 MiB [32][64][2048]
  unsigned short* gbuf   = (unsigned short*)(ws + 58720256);    // 32 MiB, reuses qkv+vt

  ln_kernel<<<ROWS/4, 256, 0, stream>>>(x, ln1w, ln1b, hbuf);
  wtrans4_kernel<<<dim3(32, 32, 4), 256, 0, stream>>>(wq, wk, wvp, wo,
      wqkvT, wqkvT + 1024*1024, wqkvT + 2*1024*1024, woT);
  wtrans_kernel<<<dim3(128, 32), 256, 0, stream>>>(w1, w1T, 1024, 4096);
  wtrans_kernel<<<dim3(32, 128), 256, 0, stream>>>(w2, w2T, 4096, 1024);
  gemm_bt<0><<<dim3(3072/128, 4096/128), 256, 0, stream>>>(hbuf, wqkvT, qkvb, nullptr, ROWS, 3072, 1024);
  vt_kernel<<<dim3(SEQ/64, BATCH*NHEAD), 256, 0, stream>>>(qkvb, vtb);
  attn_kernel<<<dim3(SEQ/64, BATCH*NHEAD), 256, 0, stream>>>(qkvb, vtb, mask, attno);
  gemm_bt<2><<<dim3(1024/128, 4096/128), 256, 0, stream>>>(attno, woT, x2, x, ROWS, 1024, 1024);
  ln_kernel<<<ROWS/4, 256, 0, stream>>>(x2, ln2w, ln2b, hbuf);
  gemm_bt<1><<<dim3(4096/128, 4096/128), 256, 0, stream>>>(hbuf, w1T, gbuf, nullptr, ROWS, FFNSZ, 1024);
  gemm_bt<2><<<dim3(1024/128, 4096/128), 256, 0, stream>>>(gbuf, w2T, out, x2, ROWS, 1024, 4096);

  (void)in_sizes; (void)n_in; (void)out_size; (void)ws_size;
}

// Round 5
// 424.145 us; speedup vs baseline: 1.1259x; 1.1259x over previous
//
#include <hip/hip_runtime.h>
#include <math.h>

// ---------------------------------------------------------------------------
// TransformerBlock: B=2 S=2048 DIM=1024 H=16 hd=64 FFN=4096, fp32 in/out.
// R4: attention reverted to R2 (R3 dbuf traded occupancy for ILP at a loss).
// GEMM rewritten: swapped MFMA operands (D = C^T tile -> lane holds 4
// consecutive output cols -> vectorized ushort4/float4 epilogue), BK=64 as
// two 32-halves (32 MFMA per barrier-pair), NT=64 tile for N=1024 GEMMs
// (grid 512 instead of 256 -> 2 blocks/CU).
// ---------------------------------------------------------------------------

#define DIMSZ 1024
#define SEQ   2048
#define BATCH 2
#define NHEAD 16
#define HD    64
#define FFNSZ 4096
#define ROWS  (BATCH*SEQ)   // 4096

typedef __attribute__((ext_vector_type(8))) short bf8_t;   // 8 x bf16 (4 VGPR)
typedef __attribute__((ext_vector_type(4))) float f4_t;    // 4 x f32

// round-to-nearest-even float -> bf16 (bit pattern)
__device__ __forceinline__ unsigned short f2bf(float f) {
  union { float f; unsigned u; } c; c.f = f;
  unsigned u = c.u;
  return (unsigned short)((u + 0x7fffu + ((u >> 16) & 1u)) >> 16);
}

__device__ __forceinline__ float fast_exp2(float x) {
#if __has_builtin(__builtin_amdgcn_exp2f)
  return __builtin_amdgcn_exp2f(x);   // v_exp_f32 is natively 2^x
#else
  return exp2f(x);
#endif
}

// pack hi16(a),hi16(b) -> (bf16(b)<<16)|bf16(a)  [truncating cvt, 1 instr]
__device__ __forceinline__ unsigned int pk_trunc_bf16(float a, float b) {
#if __has_builtin(__builtin_amdgcn_perm)
  return __builtin_amdgcn_perm(__float_as_uint(b), __float_as_uint(a), 0x07060302u);
#else
  return (__float_as_uint(b) & 0xffff0000u) | (__float_as_uint(a) >> 16);
#endif
}

__device__ __forceinline__ void async16(const void* g, void* l) {
  __builtin_amdgcn_global_load_lds((const __attribute__((address_space(1))) void*)g,
                                   (__attribute__((address_space(3))) void*)l,
                                   16, 0, 0);
}

__device__ __forceinline__ f4_t mfma_bf16(bf8_t a, bf8_t b, f4_t c) {
  return __builtin_amdgcn_mfma_f32_16x16x32_bf16(a, b, c, 0, 0, 0);
}

// ---------------------------------------------------------------------------
// LayerNorm: one wave per row of 1024 fp32 -> bf16 out.
// ---------------------------------------------------------------------------
__global__ __launch_bounds__(256) void ln_kernel(const float* __restrict__ x,
                                                 const float* __restrict__ w,
                                                 const float* __restrict__ b,
                                                 unsigned short* __restrict__ out) {
  int row  = blockIdx.x * 4 + (threadIdx.x >> 6);
  int lane = threadIdx.x & 63;
  const float4* xr = (const float4*)(x + (size_t)row * DIMSZ);
  float4 v[4];
  float s = 0.f, s2 = 0.f;
#pragma unroll
  for (int i = 0; i < 4; ++i) {
    v[i] = xr[lane + 64*i];
    s  += (v[i].x + v[i].y) + (v[i].z + v[i].w);
    s2 += (v[i].x*v[i].x + v[i].y*v[i].y) + (v[i].z*v[i].z + v[i].w*v[i].w);
  }
#pragma unroll
  for (int off = 32; off; off >>= 1) {
    s  += __shfl_xor(s,  off);
    s2 += __shfl_xor(s2, off);
  }
  float mean = s * (1.f/DIMSZ);
  float var  = s2 * (1.f/DIMSZ) - mean*mean;
  float rstd = rsqrtf(var + 1e-12f);
  const float4* wr = (const float4*)w;
  const float4* br = (const float4*)b;
#pragma unroll
  for (int i = 0; i < 4; ++i) {
    float4 wv = wr[lane + 64*i];
    float4 bv = br[lane + 64*i];
    ushort4 o;
    o.x = f2bf((v[i].x - mean) * rstd * wv.x + bv.x);
    o.y = f2bf((v[i].y - mean) * rstd * wv.y + bv.y);
    o.z = f2bf((v[i].z - mean) * rstd * wv.z + bv.z);
    o.w = f2bf((v[i].w - mean) * rstd * wv.w + bv.w);
    *(ushort4*)(out + (size_t)row * DIMSZ + (size_t)(lane + 64*i) * 4) = o;
  }
}

// ---------------------------------------------------------------------------
// Weight cast+transpose, 4 square 1024x1024 weights in one launch (grid.z).
// ---------------------------------------------------------------------------
__global__ __launch_bounds__(256) void wtrans4_kernel(const float* __restrict__ w0,
                                                      const float* __restrict__ w1,
                                                      const float* __restrict__ w2,
                                                      const float* __restrict__ w3,
                                                      unsigned short* __restrict__ o0,
                                                      unsigned short* __restrict__ o1,
                                                      unsigned short* __restrict__ o2,
                                                      unsigned short* __restrict__ o3) {
  const int K = 1024, N = 1024;
  const float* w = (blockIdx.z == 0) ? w0 : (blockIdx.z == 1) ? w1 : (blockIdx.z == 2) ? w2 : w3;
  unsigned short* wT = (blockIdx.z == 0) ? o0 : (blockIdx.z == 1) ? o1 : (blockIdx.z == 2) ? o2 : o3;
  __shared__ float t[32][33];
  int tx = threadIdx.x & 31, ty = threadIdx.x >> 5;
  int n0 = blockIdx.x * 32, k0 = blockIdx.y * 32;
#pragma unroll
  for (int i = 0; i < 4; ++i)
    t[ty + 8*i][tx] = w[(size_t)(k0 + ty + 8*i) * N + n0 + tx];
  __syncthreads();
#pragma unroll
  for (int i = 0; i < 4; ++i)
    wT[(size_t)(n0 + ty + 8*i) * K + k0 + tx] = f2bf(t[tx][ty + 8*i]);
}

// generic single-weight version (w1, w2)
__global__ __launch_bounds__(256) void wtrans_kernel(const float* __restrict__ w,
                                                     unsigned short* __restrict__ wT,
                                                     int K, int N) {
  __shared__ float t[32][33];
  int tx = threadIdx.x & 31, ty = threadIdx.x >> 5;
  int n0 = blockIdx.x * 32, k0 = blockIdx.y * 32;
#pragma unroll
  for (int i = 0; i < 4; ++i)
    t[ty + 8*i][tx] = w[(size_t)(k0 + ty + 8*i) * N + n0 + tx];
  __syncthreads();
#pragma unroll
  for (int i = 0; i < 4; ++i)
    wT[(size_t)(n0 + ty + 8*i) * K + k0 + tx] = f2bf(t[tx][ty + 8*i]);
}

// ---------------------------------------------------------------------------
// V transpose: qkv[(b*S+s)*3072 + 2048 + h*64 + d] -> vt[(bh*64+d)*S + s]
// ---------------------------------------------------------------------------
__global__ __launch_bounds__(256) void vt_kernel(const unsigned short* __restrict__ qkv,
                                                 unsigned short* __restrict__ vt) {
  __shared__ unsigned short tile[64][65];
  int bh = blockIdx.y, b = bh >> 4, h = bh & 15;
  int s0 = blockIdx.x * 64;
  int tx = threadIdx.x & 63, ty = threadIdx.x >> 6;
#pragma unroll
  for (int i = 0; i < 16; ++i) {
    int s = ty + i*4;
    tile[s][tx] = qkv[((size_t)(b*SEQ) + s0 + s) * 3072 + 2048 + h*HD + tx];
  }
  __syncthreads();
#pragma unroll
  for (int i = 0; i < 16; ++i) {
    int d = ty + i*4;
    vt[((size_t)bh * HD + d) * SEQ + s0 + tx] = tile[tx][d];
  }
}

// ---------------------------------------------------------------------------
// GEMM R4: C[M,N] = epi( A[M,K] @ Bt[N,K]^T ), A/Bt bf16 row-major.
// Swapped MFMA operands: D = (tile of C)^T, so lane (ml,quad) holds
// C[wrow+i*16+ml][wcol+j*16+quad*4 .. +3] -> vectorized epilogue.
// BK=64 staged as two 32-halves (keeps global_load_lds linear dest + the
// proven bank pattern); 32 MFMA per barrier-pair.
// NT = 128 (4 waves 64x64) or 64 (4 waves 64x32, for N=1024 outputs).
// EPI: 0 = bf16 out; 1 = bf16 gelu(exact); 2 = f32 out += res.
// grid = (N/NT, M/128).
// ---------------------------------------------------------------------------
template<int EPI, int NT>
__global__ __launch_bounds__(256) void gemm_bt(const unsigned short* __restrict__ A,
                                               const unsigned short* __restrict__ Bt,
                                               void* __restrict__ Cv,
                                               const float* __restrict__ res,
                                               int M, int N, int K) {
  constexpr int JT = NT / 32;              // j-tiles per wave (4 or 2)
  __shared__ unsigned short As[2][128][32];
  __shared__ unsigned short Bs[2][NT][32];
  int tid  = threadIdx.x;
  int wv   = tid >> 6, lane = tid & 63, quad = lane >> 4, ml = lane & 15;
  int wrow = (wv >> 1) * 64, wcol = (wv & 1) * (NT/2);
  const unsigned short* Ab = A  + (size_t)blockIdx.y * 128 * K;
  const unsigned short* Bb = Bt + (size_t)blockIdx.x * NT  * K;

  f4_t acc[4][JT];
#pragma unroll
  for (int i = 0; i < 4; ++i)
#pragma unroll
    for (int j = 0; j < JT; ++j) acc[i][j] = (f4_t){0.f, 0.f, 0.f, 0.f};

  int r0 = tid >> 2, c0 = (tid & 3) * 8;   // 64 rows x 4 chunks of 8 bf16

  for (int k0 = 0; k0 < K; k0 += 64) {
#pragma unroll
    for (int h = 0; h < 2; ++h) {
      const unsigned short* ap = Ab + (size_t)r0 * K + k0 + h*32 + c0;
      async16(ap,          &As[h][r0][c0]);
      async16(ap + 64*K,   &As[h][r0 + 64][c0]);
      const unsigned short* bp = Bb + (size_t)r0 * K + k0 + h*32 + c0;
      async16(bp,          &Bs[h][r0][c0]);
      if constexpr (NT == 128)
        async16(bp + 64*K, &Bs[h][r0 + 64][c0]);
    }
    __syncthreads();

#pragma unroll
    for (int h = 0; h < 2; ++h) {
      bf8_t af[4], bfr[JT];
#pragma unroll
      for (int i = 0; i < 4; ++i)
        af[i] = *(const bf8_t*)(&As[h][wrow + i*16 + ml][quad * 8]);
#pragma unroll
      for (int j = 0; j < JT; ++j)
        bfr[j] = *(const bf8_t*)(&Bs[h][wcol + j*16 + ml][quad * 8]);
#pragma unroll
      for (int i = 0; i < 4; ++i)
#pragma unroll
        for (int j = 0; j < JT; ++j)
          acc[i][j] = mfma_bf16(bfr[j], af[i], acc[i][j]);   // swapped: D=C^T
    }
    __syncthreads();
  }

  // epilogue: lane holds C[m = wrow+i*16+ml][n = wcol+j*16+quad*4 .. +3]
#pragma unroll
  for (int i = 0; i < 4; ++i) {
    int m = blockIdx.y * 128 + wrow + i*16 + ml;
#pragma unroll
    for (int j = 0; j < JT; ++j) {
      int n = blockIdx.x * NT + wcol + j*16 + quad*4;
      size_t off = (size_t)m * N + n;
      if constexpr (EPI == 2) {
        float4 rv = *(const float4*)(res + off);
        float4 ov;
        ov.x = rv.x + acc[i][j][0];
        ov.y = rv.y + acc[i][j][1];
        ov.z = rv.z + acc[i][j][2];
        ov.w = rv.w + acc[i][j][3];
        *(float4*)((float*)Cv + off) = ov;
      } else {
        float v0 = acc[i][j][0], v1 = acc[i][j][1], v2 = acc[i][j][2], v3 = acc[i][j][3];
        if constexpr (EPI == 1) {
          v0 = 0.5f * v0 * (1.f + erff(v0 * 0.70710678118654752f));
          v1 = 0.5f * v1 * (1.f + erff(v1 * 0.70710678118654752f));
          v2 = 0.5f * v2 * (1.f + erff(v2 * 0.70710678118654752f));
          v3 = 0.5f * v3 * (1.f + erff(v3 * 0.70710678118654752f));
        }
        ushort4 o;
        o.x = f2bf(v0); o.y = f2bf(v1); o.z = f2bf(v2); o.w = f2bf(v3);
        *(ushort4*)((unsigned short*)Cv + off) = o;
      }
    }
  }
}

// ---------------------------------------------------------------------------
// Flash attention (R2 version — best measured). grid = (S/64, B*H), block 256
// (4 waves x 16 q-rows). 64-key chunks, K/V via global_load_lds. Fixed-base
// exp2 softmax (shift-invariant; |s|~O(3)). Mask straight to registers.
// S^T = K·Q^T; O^T = V^T·P^T; P wave-private LDS (lgkmcnt-ordered).
// ---------------------------------------------------------------------------
__global__ __launch_bounds__(256) void attn_kernel(const unsigned short* __restrict__ qkv,
                                                   const unsigned short* __restrict__ vt,
                                                   const float* __restrict__ mask,
                                                   unsigned short* __restrict__ attnout) {
  __shared__ unsigned short Ks[2][64][32];   // [d-half][key][d32]   8 KB
  __shared__ unsigned short Vs[2][64][32];   // [key-half][d][k32]   8 KB
  __shared__ unsigned short Ps[4][16][72];   // per-wave P^T, padded 9 KB

  int bh = blockIdx.y, b = bh >> 4, h = bh & 15;
  int tid = threadIdx.x;
  int wv = tid >> 6, lane = tid & 63;
  int quad = lane >> 4, ml = lane & 15;
  int q0 = blockIdx.x * 64;
  int q  = q0 + wv * 16 + ml;               // this lane's q row (seq pos)

  const unsigned short* qrow = qkv + ((size_t)(b*SEQ) + q) * 3072 + h*HD;
  bf8_t qf0 = *(const bf8_t*)(qrow + quad*8);
  bf8_t qf1 = *(const bf8_t*)(qrow + 32 + quad*8);

  const unsigned short* kbase = qkv + (size_t)(b*SEQ) * 3072 + DIMSZ + h*HD;
  const unsigned short* vbase = vt + (size_t)bh * HD * SEQ;
  const float* mrow = mask + (size_t)q * SEQ;

  int srow = tid >> 2;            // 0..63
  int scol = (tid & 3) * 8;       // 0,8,16,24 (ushorts)

  f4_t O[4];
#pragma unroll
  for (int dt = 0; dt < 4; ++dt) O[dt] = (f4_t){0.f, 0.f, 0.f, 0.f};
  float lR = 0.f;                 // quad-partial sum of exp

  const float C1 = 0.18033688011112042f;   // 0.125 * log2(e)
  const float C2 = 1.4426950408889634f;    // log2(e)

  for (int t0 = 0; t0 < SEQ; t0 += 64) {
    float4 mv[4];
#pragma unroll
    for (int mt = 0; mt < 4; ++mt)
      mv[mt] = *(const float4*)(mrow + t0 + mt*16 + quad*4);

    __syncthreads();   // previous chunk's K/V reads done before overwrite
#pragma unroll
    for (int dh = 0; dh < 2; ++dh)
      async16(kbase + (size_t)(t0 + srow) * 3072 + dh*32 + scol,
              &Ks[dh][0][0] + (size_t)tid * 8);
#pragma unroll
    for (int kc = 0; kc < 2; ++kc)
      async16(vbase + (size_t)srow * SEQ + t0 + kc*32 + scol,
              &Vs[kc][0][0] + (size_t)tid * 8);
    __syncthreads();   // staging visible

#pragma unroll
    for (int mt = 0; mt < 4; ++mt) {
      bf8_t kf0 = *(const bf8_t*)(&Ks[0][mt*16 + ml][quad*8]);
      bf8_t kf1 = *(const bf8_t*)(&Ks[1][mt*16 + ml][quad*8]);
      f4_t s = (f4_t){0.f, 0.f, 0.f, 0.f};
      s = mfma_bf16(kf0, qf0, s);
      s = mfma_bf16(kf1, qf1, s);
      float p0 = fast_exp2(fmaf(s[0], C1, mv[mt].x * C2));
      float p1 = fast_exp2(fmaf(s[1], C1, mv[mt].y * C2));
      float p2 = fast_exp2(fmaf(s[2], C1, mv[mt].z * C2));
      float p3 = fast_exp2(fmaf(s[3], C1, mv[mt].w * C2));
      lR += (p0 + p1) + (p2 + p3);
      uint2 pk;
      pk.x = pk_trunc_bf16(p0, p1);
      pk.y = pk_trunc_bf16(p2, p3);
      *(uint2*)(&Ps[wv][ml][mt*16 + quad*4]) = pk;
    }

#pragma unroll
    for (int kc = 0; kc < 2; ++kc) {
      bf8_t pf = *(const bf8_t*)(&Ps[wv][ml][kc*32 + quad*8]);
#pragma unroll
      for (int dt = 0; dt < 4; ++dt) {
        bf8_t vf = *(const bf8_t*)(&Vs[kc][dt*16 + ml][quad*8]);
        O[dt] = mfma_bf16(vf, pf, O[dt]);
      }
    }
  }

  lR += __shfl_xor(lR, 16);
  lR += __shfl_xor(lR, 32);
  float linv = 1.f / lR;
#pragma unroll
  for (int dt = 0; dt < 4; ++dt) {
    ushort4 o;
    o.x = f2bf(O[dt][0] * linv);
    o.y = f2bf(O[dt][1] * linv);
    o.z = f2bf(O[dt][2] * linv);
    o.w = f2bf(O[dt][3] * linv);
    *(ushort4*)(attnout + ((size_t)(b*SEQ) + q) * DIMSZ + h*HD + dt*16 + quad*4) = o;
  }
}

// ---------------------------------------------------------------------------
extern "C" void kernel_launch(void* const* d_in, const int* in_sizes, int n_in,
                              void* d_out, int out_size, void* d_ws, size_t ws_size,
                              hipStream_t stream) {
  const float* x    = (const float*)d_in[0];
  const float* mask = (const float*)d_in[1];
  const float* wq   = (const float*)d_in[2];
  const float* wk   = (const float*)d_in[3];
  const float* wvp  = (const float*)d_in[4];
  const float* wo   = (const float*)d_in[5];
  const float* w1   = (const float*)d_in[6];
  const float* w2   = (const float*)d_in[7];
  const float* ln1w = (const float*)d_in[8];
  const float* ln1b = (const float*)d_in[9];
  const float* ln2w = (const float*)d_in[10];
  const float* ln2b = (const float*)d_in[11];
  float* out = (float*)d_out;

  char* ws = (char*)d_ws;
  unsigned short* wqkvT  = (unsigned short*)(ws + 0);           //  6 MiB [3072][1024]
  unsigned short* woT    = (unsigned short*)(ws + 6291456);     //  2 MiB [1024][1024]
  unsigned short* w1T    = (unsigned short*)(ws + 8388608);     //  8 MiB [4096][1024]
  unsigned short* w2T    = (unsigned short*)(ws + 16777216);    //  8 MiB [1024][4096]
  unsigned short* attno  = (unsigned short*)(ws + 25165824);    //  8 MiB [4096][1024]
  float*          x2     = (float*)         (ws + 33554432);    // 16 MiB [4096][1024]
  unsigned short* hbuf   = (unsigned short*)(ws + 50331648);    //  8 MiB h1 then h2
  unsigned short* qkvb   = (unsigned short*)(ws + 58720256);    // 24 MiB [4096][3072]
  unsigned short* vtb    = (unsigned short*)(ws + 83886080);    //  8 MiB [32][64][2048]
  unsigned short* gbuf   = (unsigned short*)(ws + 58720256);    // 32 MiB, reuses qkv+vt

  ln_kernel<<<ROWS/4, 256, 0, stream>>>(x, ln1w, ln1b, hbuf);
  wtrans4_kernel<<<dim3(32, 32, 4), 256, 0, stream>>>(wq, wk, wvp, wo,
      wqkvT, wqkvT + 1024*1024, wqkvT + 2*1024*1024, woT);
  wtrans_kernel<<<dim3(128, 32), 256, 0, stream>>>(w1, w1T, 1024, 4096);
  wtrans_kernel<<<dim3(32, 128), 256, 0, stream>>>(w2, w2T, 4096, 1024);
  gemm_bt<0,128><<<dim3(3072/128, 4096/128), 256, 0, stream>>>(hbuf, wqkvT, qkvb, nullptr, ROWS, 3072, 1024);
  vt_kernel<<<dim3(SEQ/64, BATCH*NHEAD), 256, 0, stream>>>(qkvb, vtb);
  attn_kernel<<<dim3(SEQ/64, BATCH*NHEAD), 256, 0, stream>>>(qkvb, vtb, mask, attno);
  gemm_bt<2,64><<<dim3(1024/64, 4096/128), 256, 0, stream>>>(attno, woT, x2, x, ROWS, 1024, 1024);
  ln_kernel<<<ROWS/4, 256, 0, stream>>>(x2, ln2w, ln2b, hbuf);
  gemm_bt<1,128><<<dim3(4096/128, 4096/128), 256, 0, stream>>>(hbuf, w1T, gbuf, nullptr, ROWS, FFNSZ, 1024);
  gemm_bt<2,64><<<dim3(1024/64, 4096/128), 256, 0, stream>>>(gbuf, w2T, out, x2, ROWS, 1024, 4096);

  (void)in_sizes; (void)n_in; (void)out_size; (void)ws_size;
}

// Round 6
// 423.936 us; speedup vs baseline: 1.1265x; 1.0005x over previous
//
#include <hip/hip_runtime.h>
#include <math.h>

// ---------------------------------------------------------------------------
// TransformerBlock: B=2 S=2048 DIM=1024 H=16 hd=64 FFN=4096, fp32 in/out.
// R5: split-K flash attention. Fixed-base exp2 softmax (no running max) makes
// partial O and l LINEAR in the key axis -> split keys across 2 blocks, add
// partials in a combine pass (no rescale). Grid 1024->2048 blocks (8/CU
// scheduled vs 2.6 resident before) at unchanged 25.6 KB LDS.
// GEMMs unchanged from R4 (swapped-operand C^T epilogue, BK=64, NT=64/128).
// ---------------------------------------------------------------------------

#define DIMSZ 1024
#define SEQ   2048
#define BATCH 2
#define NHEAD 16
#define HD    64
#define FFNSZ 4096
#define ROWS  (BATCH*SEQ)   // 4096
#define KSPLIT 2
#define KRANGE (SEQ/KSPLIT) // 1024 keys per partial

typedef __attribute__((ext_vector_type(8))) short bf8_t;   // 8 x bf16 (4 VGPR)
typedef __attribute__((ext_vector_type(4))) float f4_t;    // 4 x f32

// round-to-nearest-even float -> bf16 (bit pattern)
__device__ __forceinline__ unsigned short f2bf(float f) {
  union { float f; unsigned u; } c; c.f = f;
  unsigned u = c.u;
  return (unsigned short)((u + 0x7fffu + ((u >> 16) & 1u)) >> 16);
}

__device__ __forceinline__ float bf2f(unsigned short u) {
  union { unsigned u; float f; } c; c.u = ((unsigned)u) << 16; return c.f;
}

__device__ __forceinline__ float fast_exp2(float x) {
#if __has_builtin(__builtin_amdgcn_exp2f)
  return __builtin_amdgcn_exp2f(x);   // v_exp_f32 is natively 2^x
#else
  return exp2f(x);
#endif
}

// pack hi16(a),hi16(b) -> (bf16(b)<<16)|bf16(a)  [truncating cvt, 1 instr]
__device__ __forceinline__ unsigned int pk_trunc_bf16(float a, float b) {
#if __has_builtin(__builtin_amdgcn_perm)
  return __builtin_amdgcn_perm(__float_as_uint(b), __float_as_uint(a), 0x07060302u);
#else
  return (__float_as_uint(b) & 0xffff0000u) | (__float_as_uint(a) >> 16);
#endif
}

__device__ __forceinline__ void async16(const void* g, void* l) {
  __builtin_amdgcn_global_load_lds((const __attribute__((address_space(1))) void*)g,
                                   (__attribute__((address_space(3))) void*)l,
                                   16, 0, 0);
}

__device__ __forceinline__ f4_t mfma_bf16(bf8_t a, bf8_t b, f4_t c) {
  return __builtin_amdgcn_mfma_f32_16x16x32_bf16(a, b, c, 0, 0, 0);
}

// ---------------------------------------------------------------------------
// LayerNorm: one wave per row of 1024 fp32 -> bf16 out.
// ---------------------------------------------------------------------------
__global__ __launch_bounds__(256) void ln_kernel(const float* __restrict__ x,
                                                 const float* __restrict__ w,
                                                 const float* __restrict__ b,
                                                 unsigned short* __restrict__ out) {
  int row  = blockIdx.x * 4 + (threadIdx.x >> 6);
  int lane = threadIdx.x & 63;
  const float4* xr = (const float4*)(x + (size_t)row * DIMSZ);
  float4 v[4];
  float s = 0.f, s2 = 0.f;
#pragma unroll
  for (int i = 0; i < 4; ++i) {
    v[i] = xr[lane + 64*i];
    s  += (v[i].x + v[i].y) + (v[i].z + v[i].w);
    s2 += (v[i].x*v[i].x + v[i].y*v[i].y) + (v[i].z*v[i].z + v[i].w*v[i].w);
  }
#pragma unroll
  for (int off = 32; off; off >>= 1) {
    s  += __shfl_xor(s,  off);
    s2 += __shfl_xor(s2, off);
  }
  float mean = s * (1.f/DIMSZ);
  float var  = s2 * (1.f/DIMSZ) - mean*mean;
  float rstd = rsqrtf(var + 1e-12f);
  const float4* wr = (const float4*)w;
  const float4* br = (const float4*)b;
#pragma unroll
  for (int i = 0; i < 4; ++i) {
    float4 wv = wr[lane + 64*i];
    float4 bv = br[lane + 64*i];
    ushort4 o;
    o.x = f2bf((v[i].x - mean) * rstd * wv.x + bv.x);
    o.y = f2bf((v[i].y - mean) * rstd * wv.y + bv.y);
    o.z = f2bf((v[i].z - mean) * rstd * wv.z + bv.z);
    o.w = f2bf((v[i].w - mean) * rstd * wv.w + bv.w);
    *(ushort4*)(out + (size_t)row * DIMSZ + (size_t)(lane + 64*i) * 4) = o;
  }
}

// ---------------------------------------------------------------------------
// Weight cast+transpose, 4 square 1024x1024 weights in one launch (grid.z).
// ---------------------------------------------------------------------------
__global__ __launch_bounds__(256) void wtrans4_kernel(const float* __restrict__ w0,
                                                      const float* __restrict__ w1,
                                                      const float* __restrict__ w2,
                                                      const float* __restrict__ w3,
                                                      unsigned short* __restrict__ o0,
                                                      unsigned short* __restrict__ o1,
                                                      unsigned short* __restrict__ o2,
                                                      unsigned short* __restrict__ o3) {
  const int K = 1024, N = 1024;
  const float* w = (blockIdx.z == 0) ? w0 : (blockIdx.z == 1) ? w1 : (blockIdx.z == 2) ? w2 : w3;
  unsigned short* wT = (blockIdx.z == 0) ? o0 : (blockIdx.z == 1) ? o1 : (blockIdx.z == 2) ? o2 : o3;
  __shared__ float t[32][33];
  int tx = threadIdx.x & 31, ty = threadIdx.x >> 5;
  int n0 = blockIdx.x * 32, k0 = blockIdx.y * 32;
#pragma unroll
  for (int i = 0; i < 4; ++i)
    t[ty + 8*i][tx] = w[(size_t)(k0 + ty + 8*i) * N + n0 + tx];
  __syncthreads();
#pragma unroll
  for (int i = 0; i < 4; ++i)
    wT[(size_t)(n0 + ty + 8*i) * K + k0 + tx] = f2bf(t[tx][ty + 8*i]);
}

// generic single-weight version (w1, w2)
__global__ __launch_bounds__(256) void wtrans_kernel(const float* __restrict__ w,
                                                     unsigned short* __restrict__ wT,
                                                     int K, int N) {
  __shared__ float t[32][33];
  int tx = threadIdx.x & 31, ty = threadIdx.x >> 5;
  int n0 = blockIdx.x * 32, k0 = blockIdx.y * 32;
#pragma unroll
  for (int i = 0; i < 4; ++i)
    t[ty + 8*i][tx] = w[(size_t)(k0 + ty + 8*i) * N + n0 + tx];
  __syncthreads();
#pragma unroll
  for (int i = 0; i < 4; ++i)
    wT[(size_t)(n0 + ty + 8*i) * K + k0 + tx] = f2bf(t[tx][ty + 8*i]);
}

// ---------------------------------------------------------------------------
// V transpose: qkv[(b*S+s)*3072 + 2048 + h*64 + d] -> vt[(bh*64+d)*S + s]
// ---------------------------------------------------------------------------
__global__ __launch_bounds__(256) void vt_kernel(const unsigned short* __restrict__ qkv,
                                                 unsigned short* __restrict__ vt) {
  __shared__ unsigned short tile[64][65];
  int bh = blockIdx.y, b = bh >> 4, h = bh & 15;
  int s0 = blockIdx.x * 64;
  int tx = threadIdx.x & 63, ty = threadIdx.x >> 6;
#pragma unroll
  for (int i = 0; i < 16; ++i) {
    int s = ty + i*4;
    tile[s][tx] = qkv[((size_t)(b*SEQ) + s0 + s) * 3072 + 2048 + h*HD + tx];
  }
  __syncthreads();
#pragma unroll
  for (int i = 0; i < 16; ++i) {
    int d = ty + i*4;
    vt[((size_t)bh * HD + d) * SEQ + s0 + tx] = tile[tx][d];
  }
}

// ---------------------------------------------------------------------------
// GEMM R4: C[M,N] = epi( A[M,K] @ Bt[N,K]^T ), A/Bt bf16 row-major.
// Swapped MFMA operands: D = (tile of C)^T -> vectorized epilogue.
// BK=64 as two 32-halves; NT = 128 or 64. grid = (N/NT, M/128).
// EPI: 0 = bf16 out; 1 = bf16 gelu(exact); 2 = f32 out += res.
// ---------------------------------------------------------------------------
template<int EPI, int NT>
__global__ __launch_bounds__(256) void gemm_bt(const unsigned short* __restrict__ A,
                                               const unsigned short* __restrict__ Bt,
                                               void* __restrict__ Cv,
                                               const float* __restrict__ res,
                                               int M, int N, int K) {
  constexpr int JT = NT / 32;              // j-tiles per wave (4 or 2)
  __shared__ unsigned short As[2][128][32];
  __shared__ unsigned short Bs[2][NT][32];
  int tid  = threadIdx.x;
  int wv   = tid >> 6, lane = tid & 63, quad = lane >> 4, ml = lane & 15;
  int wrow = (wv >> 1) * 64, wcol = (wv & 1) * (NT/2);
  const unsigned short* Ab = A  + (size_t)blockIdx.y * 128 * K;
  const unsigned short* Bb = Bt + (size_t)blockIdx.x * NT  * K;

  f4_t acc[4][JT];
#pragma unroll
  for (int i = 0; i < 4; ++i)
#pragma unroll
    for (int j = 0; j < JT; ++j) acc[i][j] = (f4_t){0.f, 0.f, 0.f, 0.f};

  int r0 = tid >> 2, c0 = (tid & 3) * 8;   // 64 rows x 4 chunks of 8 bf16

  for (int k0 = 0; k0 < K; k0 += 64) {
#pragma unroll
    for (int h = 0; h < 2; ++h) {
      const unsigned short* ap = Ab + (size_t)r0 * K + k0 + h*32 + c0;
      async16(ap,          &As[h][r0][c0]);
      async16(ap + 64*K,   &As[h][r0 + 64][c0]);
      const unsigned short* bp = Bb + (size_t)r0 * K + k0 + h*32 + c0;
      async16(bp,          &Bs[h][r0][c0]);
      if constexpr (NT == 128)
        async16(bp + 64*K, &Bs[h][r0 + 64][c0]);
    }
    __syncthreads();

#pragma unroll
    for (int h = 0; h < 2; ++h) {
      bf8_t af[4], bfr[JT];
#pragma unroll
      for (int i = 0; i < 4; ++i)
        af[i] = *(const bf8_t*)(&As[h][wrow + i*16 + ml][quad * 8]);
#pragma unroll
      for (int j = 0; j < JT; ++j)
        bfr[j] = *(const bf8_t*)(&Bs[h][wcol + j*16 + ml][quad * 8]);
#pragma unroll
      for (int i = 0; i < 4; ++i)
#pragma unroll
        for (int j = 0; j < JT; ++j)
          acc[i][j] = mfma_bf16(bfr[j], af[i], acc[i][j]);   // swapped: D=C^T
    }
    __syncthreads();
  }

  // epilogue: lane holds C[m = wrow+i*16+ml][n = wcol+j*16+quad*4 .. +3]
#pragma unroll
  for (int i = 0; i < 4; ++i) {
    int m = blockIdx.y * 128 + wrow + i*16 + ml;
#pragma unroll
    for (int j = 0; j < JT; ++j) {
      int n = blockIdx.x * NT + wcol + j*16 + quad*4;
      size_t off = (size_t)m * N + n;
      if constexpr (EPI == 2) {
        float4 rv = *(const float4*)(res + off);
        float4 ov;
        ov.x = rv.x + acc[i][j][0];
        ov.y = rv.y + acc[i][j][1];
        ov.z = rv.z + acc[i][j][2];
        ov.w = rv.w + acc[i][j][3];
        *(float4*)((float*)Cv + off) = ov;
      } else {
        float v0 = acc[i][j][0], v1 = acc[i][j][1], v2 = acc[i][j][2], v3 = acc[i][j][3];
        if constexpr (EPI == 1) {
          v0 = 0.5f * v0 * (1.f + erff(v0 * 0.70710678118654752f));
          v1 = 0.5f * v1 * (1.f + erff(v1 * 0.70710678118654752f));
          v2 = 0.5f * v2 * (1.f + erff(v2 * 0.70710678118654752f));
          v3 = 0.5f * v3 * (1.f + erff(v3 * 0.70710678118654752f));
        }
        ushort4 o;
        o.x = f2bf(v0); o.y = f2bf(v1); o.z = f2bf(v2); o.w = f2bf(v3);
        *(ushort4*)((unsigned short*)Cv + off) = o;
      }
    }
  }
}

// ---------------------------------------------------------------------------
// Flash attention partial, split-K. grid = (S/64, KSPLIT, B*H), block 256.
// Each block: 64 q-rows x KRANGE keys. Fixed-base exp2 softmax is LINEAR in
// the key axis -> partial O (bf16) and l (f32) just add in the combine pass.
// Structure identical to the measured-best R2 kernel, 16 chunks instead of 32.
// ---------------------------------------------------------------------------
__global__ __launch_bounds__(256) void attn_part(const unsigned short* __restrict__ qkv,
                                                 const unsigned short* __restrict__ vt,
                                                 const float* __restrict__ mask,
                                                 unsigned short* __restrict__ pbuf,
                                                 float* __restrict__ lbuf) {
  __shared__ unsigned short Ks[2][64][32];   // [d-half][key][d32]   8 KB
  __shared__ unsigned short Vs[2][64][32];   // [key-half][d][k32]   8 KB
  __shared__ unsigned short Ps[4][16][72];   // per-wave P^T, padded 9 KB

  int kz = blockIdx.y;
  int bh = blockIdx.z, b = bh >> 4, h = bh & 15;
  int tid = threadIdx.x;
  int wv = tid >> 6, lane = tid & 63;
  int quad = lane >> 4, ml = lane & 15;
  int q0 = blockIdx.x * 64;
  int q  = q0 + wv * 16 + ml;               // this lane's q row (seq pos)
  int kbeg = kz * KRANGE;                   // first key of this partial

  const unsigned short* qrow = qkv + ((size_t)(b*SEQ) + q) * 3072 + h*HD;
  bf8_t qf0 = *(const bf8_t*)(qrow + quad*8);
  bf8_t qf1 = *(const bf8_t*)(qrow + 32 + quad*8);

  const unsigned short* kbase = qkv + ((size_t)(b*SEQ) + kbeg) * 3072 + DIMSZ + h*HD;
  const unsigned short* vbase = vt + (size_t)bh * HD * SEQ + kbeg;
  const float* mrow = mask + (size_t)q * SEQ + kbeg;

  int srow = tid >> 2;            // 0..63
  int scol = (tid & 3) * 8;       // 0,8,16,24 (ushorts)

  f4_t O[4];
#pragma unroll
  for (int dt = 0; dt < 4; ++dt) O[dt] = (f4_t){0.f, 0.f, 0.f, 0.f};
  float lR = 0.f;                 // quad-partial sum of exp

  const float C1 = 0.18033688011112042f;   // 0.125 * log2(e)
  const float C2 = 1.4426950408889634f;    // log2(e)

  for (int t0 = 0; t0 < KRANGE; t0 += 64) {
    float4 mv[4];
#pragma unroll
    for (int mt = 0; mt < 4; ++mt)
      mv[mt] = *(const float4*)(mrow + t0 + mt*16 + quad*4);

    __syncthreads();   // previous chunk's K/V reads done before overwrite
#pragma unroll
    for (int dh = 0; dh < 2; ++dh)
      async16(kbase + (size_t)(t0 + srow) * 3072 + dh*32 + scol,
              &Ks[dh][0][0] + (size_t)tid * 8);
#pragma unroll
    for (int kc = 0; kc < 2; ++kc)
      async16(vbase + (size_t)srow * SEQ + t0 + kc*32 + scol,
              &Vs[kc][0][0] + (size_t)tid * 8);
    __syncthreads();   // staging visible

#pragma unroll
    for (int mt = 0; mt < 4; ++mt) {
      bf8_t kf0 = *(const bf8_t*)(&Ks[0][mt*16 + ml][quad*8]);
      bf8_t kf1 = *(const bf8_t*)(&Ks[1][mt*16 + ml][quad*8]);
      f4_t s = (f4_t){0.f, 0.f, 0.f, 0.f};
      s = mfma_bf16(kf0, qf0, s);
      s = mfma_bf16(kf1, qf1, s);
      float p0 = fast_exp2(fmaf(s[0], C1, mv[mt].x * C2));
      float p1 = fast_exp2(fmaf(s[1], C1, mv[mt].y * C2));
      float p2 = fast_exp2(fmaf(s[2], C1, mv[mt].z * C2));
      float p3 = fast_exp2(fmaf(s[3], C1, mv[mt].w * C2));
      lR += (p0 + p1) + (p2 + p3);
      uint2 pk;
      pk.x = pk_trunc_bf16(p0, p1);
      pk.y = pk_trunc_bf16(p2, p3);
      *(uint2*)(&Ps[wv][ml][mt*16 + quad*4]) = pk;
    }

#pragma unroll
    for (int kc = 0; kc < 2; ++kc) {
      bf8_t pf = *(const bf8_t*)(&Ps[wv][ml][kc*32 + quad*8]);
#pragma unroll
      for (int dt = 0; dt < 4; ++dt) {
        bf8_t vf = *(const bf8_t*)(&Vs[kc][dt*16 + ml][quad*8]);
        O[dt] = mfma_bf16(vf, pf, O[dt]);
      }
    }
  }

  // reduce l over the 4 quads sharing this q; write partials (no divide)
  lR += __shfl_xor(lR, 16);
  lR += __shfl_xor(lR, 32);
  size_t pb = ((size_t)(bh * KSPLIT + kz) * SEQ + q) * HD;
#pragma unroll
  for (int dt = 0; dt < 4; ++dt) {
    ushort4 o;
    o.x = f2bf(O[dt][0]);
    o.y = f2bf(O[dt][1]);
    o.z = f2bf(O[dt][2]);
    o.w = f2bf(O[dt][3]);
    *(ushort4*)(pbuf + pb + dt*16 + quad*4) = o;
  }
  if (quad == 0)
    lbuf[(size_t)(bh * KSPLIT + kz) * SEQ + q] = lR;
}

// ---------------------------------------------------------------------------
// Combine: O = (O0 + O1) / (l0 + l1), bf16 out in [b,s,h*64+d] layout.
// grid = BH*SEQ*(HD/4)/256 = 4096 blocks.
// ---------------------------------------------------------------------------
__global__ __launch_bounds__(256) void attn_combine(const unsigned short* __restrict__ pbuf,
                                                    const float* __restrict__ lbuf,
                                                    unsigned short* __restrict__ attno) {
  int t = blockIdx.x * 256 + threadIdx.x;   // [0, BH*SEQ*16)
  int dchunk = t & 15;
  int q = (t >> 4) & (SEQ - 1);
  int bh = t >> 15;                         // SEQ*16 = 32768 = 2^15
  int b = bh >> 4, h = bh & 15;
  size_t o0 = ((size_t)(bh * KSPLIT + 0) * SEQ + q) * HD + dchunk * 4;
  size_t o1 = ((size_t)(bh * KSPLIT + 1) * SEQ + q) * HD + dchunk * 4;
  ushort4 a = *(const ushort4*)(pbuf + o0);
  ushort4 c = *(const ushort4*)(pbuf + o1);
  float l = lbuf[(size_t)(bh * KSPLIT + 0) * SEQ + q]
          + lbuf[(size_t)(bh * KSPLIT + 1) * SEQ + q];
  float inv = 1.f / l;
  ushort4 o;
  o.x = f2bf((bf2f(a.x) + bf2f(c.x)) * inv);
  o.y = f2bf((bf2f(a.y) + bf2f(c.y)) * inv);
  o.z = f2bf((bf2f(a.z) + bf2f(c.z)) * inv);
  o.w = f2bf((bf2f(a.w) + bf2f(c.w)) * inv);
  *(ushort4*)(attno + ((size_t)(b*SEQ) + q) * DIMSZ + h*HD + dchunk*4) = o;
}

// ---------------------------------------------------------------------------
extern "C" void kernel_launch(void* const* d_in, const int* in_sizes, int n_in,
                              void* d_out, int out_size, void* d_ws, size_t ws_size,
                              hipStream_t stream) {
  const float* x    = (const float*)d_in[0];
  const float* mask = (const float*)d_in[1];
  const float* wq   = (const float*)d_in[2];
  const float* wk   = (const float*)d_in[3];
  const float* wvp  = (const float*)d_in[4];
  const float* wo   = (const float*)d_in[5];
  const float* w1   = (const float*)d_in[6];
  const float* w2   = (const float*)d_in[7];
  const float* ln1w = (const float*)d_in[8];
  const float* ln1b = (const float*)d_in[9];
  const float* ln2w = (const float*)d_in[10];
  const float* ln2b = (const float*)d_in[11];
  float* out = (float*)d_out;

  char* ws = (char*)d_ws;
  unsigned short* wqkvT  = (unsigned short*)(ws + 0);           //  6 MiB [3072][1024]
  unsigned short* woT    = (unsigned short*)(ws + 6291456);     //  2 MiB [1024][1024]
  unsigned short* w1T    = (unsigned short*)(ws + 8388608);     //  8 MiB [4096][1024]
  unsigned short* w2T    = (unsigned short*)(ws + 16777216);    //  8 MiB [1024][4096]
  unsigned short* attno  = (unsigned short*)(ws + 25165824);    //  8 MiB [4096][1024]
  float*          x2     = (float*)         (ws + 33554432);    // 16 MiB [4096][1024]
  unsigned short* hbuf   = (unsigned short*)(ws + 50331648);    //  8 MiB h1 then h2
  unsigned short* qkvb   = (unsigned short*)(ws + 58720256);    // 24 MiB [4096][3072]
  unsigned short* vtb    = (unsigned short*)(ws + 83886080);    //  8 MiB [32][64][2048]
  unsigned short* gbuf   = (unsigned short*)(ws + 58720256);    // 32 MiB, reuses qkv+vt
  // split-K attention partials — time-multiplexed regions:
  //   pbuf (16 MiB bf16 [BH][KSPLIT][SEQ][HD]) lives in x2's region: written
  //   by attn_part, read by combine, BEFORE the WO gemm writes x2.
  //   lbuf (512 KiB f32) lives at hbuf start: h1 already consumed by the QKV
  //   gemm; ln2 rewrites hbuf only after combine.
  unsigned short* pbuf   = (unsigned short*)(ws + 33554432);
  float*          lbuf   = (float*)         (ws + 50331648);

  ln_kernel<<<ROWS/4, 256, 0, stream>>>(x, ln1w, ln1b, hbuf);
  wtrans4_kernel<<<dim3(32, 32, 4), 256, 0, stream>>>(wq, wk, wvp, wo,
      wqkvT, wqkvT + 1024*1024, wqkvT + 2*1024*1024, woT);
  wtrans_kernel<<<dim3(128, 32), 256, 0, stream>>>(w1, w1T, 1024, 4096);
  wtrans_kernel<<<dim3(32, 128), 256, 0, stream>>>(w2, w2T, 4096, 1024);
  gemm_bt<0,128><<<dim3(3072/128, 4096/128), 256, 0, stream>>>(hbuf, wqkvT, qkvb, nullptr, ROWS, 3072, 1024);
  vt_kernel<<<dim3(SEQ/64, BATCH*NHEAD), 256, 0, stream>>>(qkvb, vtb);
  attn_part<<<dim3(SEQ/64, KSPLIT, BATCH*NHEAD), 256, 0, stream>>>(qkvb, vtb, mask, pbuf, lbuf);
  attn_combine<<<(BATCH*NHEAD*SEQ*(HD/4))/256, 256, 0, stream>>>(pbuf, lbuf, attno);
  gemm_bt<2,64><<<dim3(1024/64, 4096/128), 256, 0, stream>>>(attno, woT, x2, x, ROWS, 1024, 1024);
  ln_kernel<<<ROWS/4, 256, 0, stream>>>(x2, ln2w, ln2b, hbuf);
  gemm_bt<1,128><<<dim3(4096/128, 4096/128), 256, 0, stream>>>(hbuf, w1T, gbuf, nullptr, ROWS, FFNSZ, 1024);
  gemm_bt<2,64><<<dim3(1024/64, 4096/128), 256, 0, stream>>>(gbuf, w2T, out, x2, ROWS, 1024, 4096);

  (void)in_sizes; (void)n_in; (void)out_size; (void)ws_size;
}

// Round 7
// 411.782 us; speedup vs baseline: 1.1598x; 1.0295x over previous
//
#include <hip/hip_runtime.h>
#include <math.h>

// ---------------------------------------------------------------------------
// TransformerBlock: B=2 S=2048 DIM=1024 H=16 hd=64 FFN=4096, fp32 in/out.
// R6: attention is LDS-BW-bound (each wave re-reads whole K/V tiles; ~3.1 GB
// LDS traffic ≈ 60 µs at measured b128 rate). Fix: 128 q-rows per block
// (2 Q-frags per wave) -> K/V LDS reads amortized over 2x MFMAs, block count
// halves, aggregate LDS traffic -45%. Split-K (KSPLIT=2) retained.
// GEMMs unchanged from R4 (swapped-operand C^T epilogue, BK=64, NT=64/128).
// ---------------------------------------------------------------------------

#define DIMSZ 1024
#define SEQ   2048
#define BATCH 2
#define NHEAD 16
#define HD    64
#define FFNSZ 4096
#define ROWS  (BATCH*SEQ)   // 4096
#define KSPLIT 2
#define KRANGE (SEQ/KSPLIT) // 1024 keys per partial

typedef __attribute__((ext_vector_type(8))) short bf8_t;   // 8 x bf16 (4 VGPR)
typedef __attribute__((ext_vector_type(4))) float f4_t;    // 4 x f32

// round-to-nearest-even float -> bf16 (bit pattern)
__device__ __forceinline__ unsigned short f2bf(float f) {
  union { float f; unsigned u; } c; c.f = f;
  unsigned u = c.u;
  return (unsigned short)((u + 0x7fffu + ((u >> 16) & 1u)) >> 16);
}

__device__ __forceinline__ float bf2f(unsigned short u) {
  union { unsigned u; float f; } c; c.u = ((unsigned)u) << 16; return c.f;
}

__device__ __forceinline__ float fast_exp2(float x) {
#if __has_builtin(__builtin_amdgcn_exp2f)
  return __builtin_amdgcn_exp2f(x);   // v_exp_f32 is natively 2^x
#else
  return exp2f(x);
#endif
}

// pack hi16(a),hi16(b) -> (bf16(b)<<16)|bf16(a)  [truncating cvt, 1 instr]
__device__ __forceinline__ unsigned int pk_trunc_bf16(float a, float b) {
#if __has_builtin(__builtin_amdgcn_perm)
  return __builtin_amdgcn_perm(__float_as_uint(b), __float_as_uint(a), 0x07060302u);
#else
  return (__float_as_uint(b) & 0xffff0000u) | (__float_as_uint(a) >> 16);
#endif
}

__device__ __forceinline__ void async16(const void* g, void* l) {
  __builtin_amdgcn_global_load_lds((const __attribute__((address_space(1))) void*)g,
                                   (__attribute__((address_space(3))) void*)l,
                                   16, 0, 0);
}

__device__ __forceinline__ f4_t mfma_bf16(bf8_t a, bf8_t b, f4_t c) {
  return __builtin_amdgcn_mfma_f32_16x16x32_bf16(a, b, c, 0, 0, 0);
}

// ---------------------------------------------------------------------------
// LayerNorm: one wave per row of 1024 fp32 -> bf16 out.
// ---------------------------------------------------------------------------
__global__ __launch_bounds__(256) void ln_kernel(const float* __restrict__ x,
                                                 const float* __restrict__ w,
                                                 const float* __restrict__ b,
                                                 unsigned short* __restrict__ out) {
  int row  = blockIdx.x * 4 + (threadIdx.x >> 6);
  int lane = threadIdx.x & 63;
  const float4* xr = (const float4*)(x + (size_t)row * DIMSZ);
  float4 v[4];
  float s = 0.f, s2 = 0.f;
#pragma unroll
  for (int i = 0; i < 4; ++i) {
    v[i] = xr[lane + 64*i];
    s  += (v[i].x + v[i].y) + (v[i].z + v[i].w);
    s2 += (v[i].x*v[i].x + v[i].y*v[i].y) + (v[i].z*v[i].z + v[i].w*v[i].w);
  }
#pragma unroll
  for (int off = 32; off; off >>= 1) {
    s  += __shfl_xor(s,  off);
    s2 += __shfl_xor(s2, off);
  }
  float mean = s * (1.f/DIMSZ);
  float var  = s2 * (1.f/DIMSZ) - mean*mean;
  float rstd = rsqrtf(var + 1e-12f);
  const float4* wr = (const float4*)w;
  const float4* br = (const float4*)b;
#pragma unroll
  for (int i = 0; i < 4; ++i) {
    float4 wv = wr[lane + 64*i];
    float4 bv = br[lane + 64*i];
    ushort4 o;
    o.x = f2bf((v[i].x - mean) * rstd * wv.x + bv.x);
    o.y = f2bf((v[i].y - mean) * rstd * wv.y + bv.y);
    o.z = f2bf((v[i].z - mean) * rstd * wv.z + bv.z);
    o.w = f2bf((v[i].w - mean) * rstd * wv.w + bv.w);
    *(ushort4*)(out + (size_t)row * DIMSZ + (size_t)(lane + 64*i) * 4) = o;
  }
}

// ---------------------------------------------------------------------------
// Weight cast+transpose, 4 square 1024x1024 weights in one launch (grid.z).
// ---------------------------------------------------------------------------
__global__ __launch_bounds__(256) void wtrans4_kernel(const float* __restrict__ w0,
                                                      const float* __restrict__ w1,
                                                      const float* __restrict__ w2,
                                                      const float* __restrict__ w3,
                                                      unsigned short* __restrict__ o0,
                                                      unsigned short* __restrict__ o1,
                                                      unsigned short* __restrict__ o2,
                                                      unsigned short* __restrict__ o3) {
  const int K = 1024, N = 1024;
  const float* w = (blockIdx.z == 0) ? w0 : (blockIdx.z == 1) ? w1 : (blockIdx.z == 2) ? w2 : w3;
  unsigned short* wT = (blockIdx.z == 0) ? o0 : (blockIdx.z == 1) ? o1 : (blockIdx.z == 2) ? o2 : o3;
  __shared__ float t[32][33];
  int tx = threadIdx.x & 31, ty = threadIdx.x >> 5;
  int n0 = blockIdx.x * 32, k0 = blockIdx.y * 32;
#pragma unroll
  for (int i = 0; i < 4; ++i)
    t[ty + 8*i][tx] = w[(size_t)(k0 + ty + 8*i) * N + n0 + tx];
  __syncthreads();
#pragma unroll
  for (int i = 0; i < 4; ++i)
    wT[(size_t)(n0 + ty + 8*i) * K + k0 + tx] = f2bf(t[tx][ty + 8*i]);
}

// generic single-weight version (w1, w2)
__global__ __launch_bounds__(256) void wtrans_kernel(const float* __restrict__ w,
                                                     unsigned short* __restrict__ wT,
                                                     int K, int N) {
  __shared__ float t[32][33];
  int tx = threadIdx.x & 31, ty = threadIdx.x >> 5;
  int n0 = blockIdx.x * 32, k0 = blockIdx.y * 32;
#pragma unroll
  for (int i = 0; i < 4; ++i)
    t[ty + 8*i][tx] = w[(size_t)(k0 + ty + 8*i) * N + n0 + tx];
  __syncthreads();
#pragma unroll
  for (int i = 0; i < 4; ++i)
    wT[(size_t)(n0 + ty + 8*i) * K + k0 + tx] = f2bf(t[tx][ty + 8*i]);
}

// ---------------------------------------------------------------------------
// V transpose: qkv[(b*S+s)*3072 + 2048 + h*64 + d] -> vt[(bh*64+d)*S + s]
// ---------------------------------------------------------------------------
__global__ __launch_bounds__(256) void vt_kernel(const unsigned short* __restrict__ qkv,
                                                 unsigned short* __restrict__ vt) {
  __shared__ unsigned short tile[64][65];
  int bh = blockIdx.y, b = bh >> 4, h = bh & 15;
  int s0 = blockIdx.x * 64;
  int tx = threadIdx.x & 63, ty = threadIdx.x >> 6;
#pragma unroll
  for (int i = 0; i < 16; ++i) {
    int s = ty + i*4;
    tile[s][tx] = qkv[((size_t)(b*SEQ) + s0 + s) * 3072 + 2048 + h*HD + tx];
  }
  __syncthreads();
#pragma unroll
  for (int i = 0; i < 16; ++i) {
    int d = ty + i*4;
    vt[((size_t)bh * HD + d) * SEQ + s0 + tx] = tile[tx][d];
  }
}

// ---------------------------------------------------------------------------
// GEMM R4: C[M,N] = epi( A[M,K] @ Bt[N,K]^T ), A/Bt bf16 row-major.
// Swapped MFMA operands: D = (tile of C)^T -> vectorized epilogue.
// BK=64 as two 32-halves; NT = 128 or 64. grid = (N/NT, M/128).
// EPI: 0 = bf16 out; 1 = bf16 gelu(exact); 2 = f32 out += res.
// ---------------------------------------------------------------------------
template<int EPI, int NT>
__global__ __launch_bounds__(256) void gemm_bt(const unsigned short* __restrict__ A,
                                               const unsigned short* __restrict__ Bt,
                                               void* __restrict__ Cv,
                                               const float* __restrict__ res,
                                               int M, int N, int K) {
  constexpr int JT = NT / 32;              // j-tiles per wave (4 or 2)
  __shared__ unsigned short As[2][128][32];
  __shared__ unsigned short Bs[2][NT][32];
  int tid  = threadIdx.x;
  int wv   = tid >> 6, lane = tid & 63, quad = lane >> 4, ml = lane & 15;
  int wrow = (wv >> 1) * 64, wcol = (wv & 1) * (NT/2);
  const unsigned short* Ab = A  + (size_t)blockIdx.y * 128 * K;
  const unsigned short* Bb = Bt + (size_t)blockIdx.x * NT  * K;

  f4_t acc[4][JT];
#pragma unroll
  for (int i = 0; i < 4; ++i)
#pragma unroll
    for (int j = 0; j < JT; ++j) acc[i][j] = (f4_t){0.f, 0.f, 0.f, 0.f};

  int r0 = tid >> 2, c0 = (tid & 3) * 8;   // 64 rows x 4 chunks of 8 bf16

  for (int k0 = 0; k0 < K; k0 += 64) {
#pragma unroll
    for (int h = 0; h < 2; ++h) {
      const unsigned short* ap = Ab + (size_t)r0 * K + k0 + h*32 + c0;
      async16(ap,          &As[h][r0][c0]);
      async16(ap + 64*K,   &As[h][r0 + 64][c0]);
      const unsigned short* bp = Bb + (size_t)r0 * K + k0 + h*32 + c0;
      async16(bp,          &Bs[h][r0][c0]);
      if constexpr (NT == 128)
        async16(bp + 64*K, &Bs[h][r0 + 64][c0]);
    }
    __syncthreads();

#pragma unroll
    for (int h = 0; h < 2; ++h) {
      bf8_t af[4], bfr[JT];
#pragma unroll
      for (int i = 0; i < 4; ++i)
        af[i] = *(const bf8_t*)(&As[h][wrow + i*16 + ml][quad * 8]);
#pragma unroll
      for (int j = 0; j < JT; ++j)
        bfr[j] = *(const bf8_t*)(&Bs[h][wcol + j*16 + ml][quad * 8]);
#pragma unroll
      for (int i = 0; i < 4; ++i)
#pragma unroll
        for (int j = 0; j < JT; ++j)
          acc[i][j] = mfma_bf16(bfr[j], af[i], acc[i][j]);   // swapped: D=C^T
    }
    __syncthreads();
  }

  // epilogue: lane holds C[m = wrow+i*16+ml][n = wcol+j*16+quad*4 .. +3]
#pragma unroll
  for (int i = 0; i < 4; ++i) {
    int m = blockIdx.y * 128 + wrow + i*16 + ml;
#pragma unroll
    for (int j = 0; j < JT; ++j) {
      int n = blockIdx.x * NT + wcol + j*16 + quad*4;
      size_t off = (size_t)m * N + n;
      if constexpr (EPI == 2) {
        float4 rv = *(const float4*)(res + off);
        float4 ov;
        ov.x = rv.x + acc[i][j][0];
        ov.y = rv.y + acc[i][j][1];
        ov.z = rv.z + acc[i][j][2];
        ov.w = rv.w + acc[i][j][3];
        *(float4*)((float*)Cv + off) = ov;
      } else {
        float v0 = acc[i][j][0], v1 = acc[i][j][1], v2 = acc[i][j][2], v3 = acc[i][j][3];
        if constexpr (EPI == 1) {
          v0 = 0.5f * v0 * (1.f + erff(v0 * 0.70710678118654752f));
          v1 = 0.5f * v1 * (1.f + erff(v1 * 0.70710678118654752f));
          v2 = 0.5f * v2 * (1.f + erff(v2 * 0.70710678118654752f));
          v3 = 0.5f * v3 * (1.f + erff(v3 * 0.70710678118654752f));
        }
        ushort4 o;
        o.x = f2bf(v0); o.y = f2bf(v1); o.z = f2bf(v2); o.w = f2bf(v3);
        *(ushort4*)((unsigned short*)Cv + off) = o;
      }
    }
  }
}

// ---------------------------------------------------------------------------
// Flash attention partial, R6: 128 q-rows/block, 2 Q-frags per wave.
// grid = (SEQ/128, KSPLIT, B*H), block 256. K/V LDS tiles read once per wave
// feed 2x the MFMAs (LDS-BW was the binding pipe). Fixed-base exp2 softmax
// (linear in keys -> split-K partials add). S^T = K·Q^T; O^T = V^T·P^T.
// ---------------------------------------------------------------------------
__global__ __launch_bounds__(256) void attn_part(const unsigned short* __restrict__ qkv,
                                                 const unsigned short* __restrict__ vt,
                                                 const float* __restrict__ mask,
                                                 unsigned short* __restrict__ pbuf,
                                                 float* __restrict__ lbuf) {
  __shared__ unsigned short Ks[2][64][32];      // [d-half][key][d32]   8 KB
  __shared__ unsigned short Vs[2][64][32];      // [key-half][d][k32]   8 KB
  __shared__ unsigned short Ps[4][2][16][72];   // [wave][qfrag][q][key] 18 KB

  int kz = blockIdx.y;
  int bh = blockIdx.z, b = bh >> 4, h = bh & 15;
  int tid = threadIdx.x;
  int wv = tid >> 6, lane = tid & 63;
  int quad = lane >> 4, ml = lane & 15;
  int q0 = blockIdx.x * 128;
  int qA = q0 + wv * 32 + ml;               // frag 0 q row
  int qB = qA + 16;                         // frag 1 q row
  int kbeg = kz * KRANGE;

  const unsigned short* qrowA = qkv + ((size_t)(b*SEQ) + qA) * 3072 + h*HD;
  const unsigned short* qrowB = qkv + ((size_t)(b*SEQ) + qB) * 3072 + h*HD;
  bf8_t qf[2][2];
  qf[0][0] = *(const bf8_t*)(qrowA + quad*8);
  qf[0][1] = *(const bf8_t*)(qrowA + 32 + quad*8);
  qf[1][0] = *(const bf8_t*)(qrowB + quad*8);
  qf[1][1] = *(const bf8_t*)(qrowB + 32 + quad*8);

  const unsigned short* kbase = qkv + ((size_t)(b*SEQ) + kbeg) * 3072 + DIMSZ + h*HD;
  const unsigned short* vbase = vt + (size_t)bh * HD * SEQ + kbeg;
  const float* mrowA = mask + (size_t)qA * SEQ + kbeg;
  const float* mrowB = mask + (size_t)qB * SEQ + kbeg;

  int srow = tid >> 2;            // 0..63
  int scol = (tid & 3) * 8;       // 0,8,16,24 (ushorts)

  f4_t O[2][4];
#pragma unroll
  for (int g = 0; g < 2; ++g)
#pragma unroll
    for (int dt = 0; dt < 4; ++dt) O[g][dt] = (f4_t){0.f, 0.f, 0.f, 0.f};
  float lR[2] = {0.f, 0.f};

  const float C1 = 0.18033688011112042f;   // 0.125 * log2(e)
  const float C2 = 1.4426950408889634f;    // log2(e)

  for (int t0 = 0; t0 < KRANGE; t0 += 64) {
    float4 mvA[4], mvB[4];
#pragma unroll
    for (int mt = 0; mt < 4; ++mt) {
      mvA[mt] = *(const float4*)(mrowA + t0 + mt*16 + quad*4);
      mvB[mt] = *(const float4*)(mrowB + t0 + mt*16 + quad*4);
    }

    __syncthreads();   // previous chunk's K/V reads done before overwrite
#pragma unroll
    for (int dh = 0; dh < 2; ++dh)
      async16(kbase + (size_t)(t0 + srow) * 3072 + dh*32 + scol,
              &Ks[dh][0][0] + (size_t)tid * 8);
#pragma unroll
    for (int kc = 0; kc < 2; ++kc)
      async16(vbase + (size_t)srow * SEQ + t0 + kc*32 + scol,
              &Vs[kc][0][0] + (size_t)tid * 8);
    __syncthreads();   // staging visible

    // --- S^T = K·Q^T over 64 keys, both q-frags share the K reads ---
#pragma unroll
    for (int mt = 0; mt < 4; ++mt) {
      bf8_t kf0 = *(const bf8_t*)(&Ks[0][mt*16 + ml][quad*8]);
      bf8_t kf1 = *(const bf8_t*)(&Ks[1][mt*16 + ml][quad*8]);
#pragma unroll
      for (int g = 0; g < 2; ++g) {
        f4_t s = (f4_t){0.f, 0.f, 0.f, 0.f};
        s = mfma_bf16(kf0, qf[g][0], s);
        s = mfma_bf16(kf1, qf[g][1], s);
        const float4& mv = g ? mvB[mt] : mvA[mt];
        float p0 = fast_exp2(fmaf(s[0], C1, mv.x * C2));
        float p1 = fast_exp2(fmaf(s[1], C1, mv.y * C2));
        float p2 = fast_exp2(fmaf(s[2], C1, mv.z * C2));
        float p3 = fast_exp2(fmaf(s[3], C1, mv.w * C2));
        lR[g] += (p0 + p1) + (p2 + p3);
        uint2 pk;
        pk.x = pk_trunc_bf16(p0, p1);
        pk.y = pk_trunc_bf16(p2, p3);
        *(uint2*)(&Ps[wv][g][ml][mt*16 + quad*4]) = pk;
      }
    }

    // --- O^T += V^T·P^T, both q-frags share the V reads ---
#pragma unroll
    for (int kc = 0; kc < 2; ++kc) {
      bf8_t pfA = *(const bf8_t*)(&Ps[wv][0][ml][kc*32 + quad*8]);
      bf8_t pfB = *(const bf8_t*)(&Ps[wv][1][ml][kc*32 + quad*8]);
#pragma unroll
      for (int dt = 0; dt < 4; ++dt) {
        bf8_t vf = *(const bf8_t*)(&Vs[kc][dt*16 + ml][quad*8]);
        O[0][dt] = mfma_bf16(vf, pfA, O[0][dt]);
        O[1][dt] = mfma_bf16(vf, pfB, O[1][dt]);
      }
    }
  }

  // reduce l over quads; write partials (no divide)
#pragma unroll
  for (int g = 0; g < 2; ++g) {
    lR[g] += __shfl_xor(lR[g], 16);
    lR[g] += __shfl_xor(lR[g], 32);
    int q = g ? qB : qA;
    size_t pb = ((size_t)(bh * KSPLIT + kz) * SEQ + q) * HD;
#pragma unroll
    for (int dt = 0; dt < 4; ++dt) {
      ushort4 o;
      o.x = f2bf(O[g][dt][0]);
      o.y = f2bf(O[g][dt][1]);
      o.z = f2bf(O[g][dt][2]);
      o.w = f2bf(O[g][dt][3]);
      *(ushort4*)(pbuf + pb + dt*16 + quad*4) = o;
    }
    if (quad == 0)
      lbuf[(size_t)(bh * KSPLIT + kz) * SEQ + q] = lR[g];
  }
}

// ---------------------------------------------------------------------------
// Combine: O = (O0 + O1) / (l0 + l1), bf16 out in [b,s,h*64+d] layout.
// grid = BH*SEQ*(HD/4)/256 = 4096 blocks.
// ---------------------------------------------------------------------------
__global__ __launch_bounds__(256) void attn_combine(const unsigned short* __restrict__ pbuf,
                                                    const float* __restrict__ lbuf,
                                                    unsigned short* __restrict__ attno) {
  int t = blockIdx.x * 256 + threadIdx.x;   // [0, BH*SEQ*16)
  int dchunk = t & 15;
  int q = (t >> 4) & (SEQ - 1);
  int bh = t >> 15;                         // SEQ*16 = 32768 = 2^15
  int b = bh >> 4, h = bh & 15;
  size_t o0 = ((size_t)(bh * KSPLIT + 0) * SEQ + q) * HD + dchunk * 4;
  size_t o1 = ((size_t)(bh * KSPLIT + 1) * SEQ + q) * HD + dchunk * 4;
  ushort4 a = *(const ushort4*)(pbuf + o0);
  ushort4 c = *(const ushort4*)(pbuf + o1);
  float l = lbuf[(size_t)(bh * KSPLIT + 0) * SEQ + q]
          + lbuf[(size_t)(bh * KSPLIT + 1) * SEQ + q];
  float inv = 1.f / l;
  ushort4 o;
  o.x = f2bf((bf2f(a.x) + bf2f(c.x)) * inv);
  o.y = f2bf((bf2f(a.y) + bf2f(c.y)) * inv);
  o.z = f2bf((bf2f(a.z) + bf2f(c.z)) * inv);
  o.w = f2bf((bf2f(a.w) + bf2f(c.w)) * inv);
  *(ushort4*)(attno + ((size_t)(b*SEQ) + q) * DIMSZ + h*HD + dchunk*4) = o;
}

// ---------------------------------------------------------------------------
extern "C" void kernel_launch(void* const* d_in, const int* in_sizes, int n_in,
                              void* d_out, int out_size, void* d_ws, size_t ws_size,
                              hipStream_t stream) {
  const float* x    = (const float*)d_in[0];
  const float* mask = (const float*)d_in[1];
  const float* wq   = (const float*)d_in[2];
  const float* wk   = (const float*)d_in[3];
  const float* wvp  = (const float*)d_in[4];
  const float* wo   = (const float*)d_in[5];
  const float* w1   = (const float*)d_in[6];
  const float* w2   = (const float*)d_in[7];
  const float* ln1w = (const float*)d_in[8];
  const float* ln1b = (const float*)d_in[9];
  const float* ln2w = (const float*)d_in[10];
  const float* ln2b = (const float*)d_in[11];
  float* out = (float*)d_out;

  char* ws = (char*)d_ws;
  unsigned short* wqkvT  = (unsigned short*)(ws + 0);           //  6 MiB [3072][1024]
  unsigned short* woT    = (unsigned short*)(ws + 6291456);     //  2 MiB [1024][1024]
  unsigned short* w1T    = (unsigned short*)(ws + 8388608);     //  8 MiB [4096][1024]
  unsigned short* w2T    = (unsigned short*)(ws + 16777216);    //  8 MiB [1024][4096]
  unsigned short* attno  = (unsigned short*)(ws + 25165824);    //  8 MiB [4096][1024]
  float*          x2     = (float*)         (ws + 33554432);    // 16 MiB [4096][1024]
  unsigned short* hbuf   = (unsigned short*)(ws + 50331648);    //  8 MiB h1 then h2
  unsigned short* qkvb   = (unsigned short*)(ws + 58720256);    // 24 MiB [4096][3072]
  unsigned short* vtb    = (unsigned short*)(ws + 83886080);    //  8 MiB [32][64][2048]
  unsigned short* gbuf   = (unsigned short*)(ws + 58720256);    // 32 MiB, reuses qkv+vt
  // split-K partials: pbuf in x2's region (consumed by combine before WO gemm
  // writes x2); lbuf at hbuf start (h1 already consumed; ln2 rewrites later).
  unsigned short* pbuf   = (unsigned short*)(ws + 33554432);
  float*          lbuf   = (float*)         (ws + 50331648);

  ln_kernel<<<ROWS/4, 256, 0, stream>>>(x, ln1w, ln1b, hbuf);
  wtrans4_kernel<<<dim3(32, 32, 4), 256, 0, stream>>>(wq, wk, wvp, wo,
      wqkvT, wqkvT + 1024*1024, wqkvT + 2*1024*1024, woT);
  wtrans_kernel<<<dim3(128, 32), 256, 0, stream>>>(w1, w1T, 1024, 4096);
  wtrans_kernel<<<dim3(32, 128), 256, 0, stream>>>(w2, w2T, 4096, 1024);
  gemm_bt<0,128><<<dim3(3072/128, 4096/128), 256, 0, stream>>>(hbuf, wqkvT, qkvb, nullptr, ROWS, 3072, 1024);
  vt_kernel<<<dim3(SEQ/64, BATCH*NHEAD), 256, 0, stream>>>(qkvb, vtb);
  attn_part<<<dim3(SEQ/128, KSPLIT, BATCH*NHEAD), 256, 0, stream>>>(qkvb, vtb, mask, pbuf, lbuf);
  attn_combine<<<(BATCH*NHEAD*SEQ*(HD/4))/256, 256, 0, stream>>>(pbuf, lbuf, attno);
  gemm_bt<2,64><<<dim3(1024/64, 4096/128), 256, 0, stream>>>(attno, woT, x2, x, ROWS, 1024, 1024);
  ln_kernel<<<ROWS/4, 256, 0, stream>>>(x2, ln2w, ln2b, hbuf);
  gemm_bt<1,128><<<dim3(4096/128, 4096/128), 256, 0, stream>>>(hbuf, w1T, gbuf, nullptr, ROWS, FFNSZ, 1024);
  gemm_bt<2,64><<<dim3(1024/64, 4096/128), 256, 0, stream>>>(gbuf, w2T, out, x2, ROWS, 1024, 4096);

  (void)in_sizes; (void)n_in; (void)out_size; (void)ws_size;
}